// Round 20
// baseline (127.353 us; speedup 1.0000x reference)
//
#include <hip/hip_runtime.h>
#include <hip/hip_bf16.h>

#define SEQ 2048
#define DIMM 2048
#define NQH 32
#define NKVH 8
#define HD 64

typedef _Float16 half8 __attribute__((ext_vector_type(8)));
typedef float f32x4 __attribute__((ext_vector_type(4)));
typedef __fp16 fp16raw2 __attribute__((ext_vector_type(2)));
using fp16 = _Float16;

typedef __attribute__((address_space(1))) unsigned int ga_u32;
typedef __attribute__((address_space(3))) unsigned int ls_u32;

__device__ __forceinline__ void gll16(const void* g, void* l) {
    __builtin_amdgcn_global_load_lds((const ga_u32*)g, (ls_u32*)l, 16, 0, 0);
}

// ============ merged prep: cast x, transpose wq/wk/wv, transpose w_out, RoPE trig table ============
__global__ void prep_kernel(const float* __restrict__ x,
                            const float* __restrict__ wq, const float* __restrict__ wk,
                            const float* __restrict__ wv, const float* __restrict__ wo,
                            fp16* __restrict__ xh, fp16* __restrict__ wqkvt,
                            fp16* __restrict__ w2t, float2* __restrict__ trig) {
    __shared__ float tile[64][65];
    const int bx = blockIdx.x;
    const int t = threadIdx.x;
    if (bx < 1024) {
#pragma unroll
        for (int it = 0; it < 4; it++) {
            int i = bx * 4096 + it * 1024 + t * 4;
            float4 v = *reinterpret_cast<const float4*>(x + i);
            fp16* o = xh + i;
            o[0] = (fp16)v.x; o[1] = (fp16)v.y; o[2] = (fp16)v.z; o[3] = (fp16)v.w;
        }
    } else if (bx < 2560) {
        const int zi = bx - 1024;
        const int z = zi >> 5;
        const int r0 = (zi & 31) * 64;
        const float* inh = (z < 32) ? wq + (size_t)z * SEQ * HD
                                    : (z < 40) ? wk + (size_t)(z - 32) * SEQ * HD
                                               : wv + (size_t)(z - 40) * SEQ * HD;
        fp16* outh = wqkvt + (size_t)z * HD * SEQ;
#pragma unroll
        for (int i = 0; i < 16; i++) {
            int idx = i * 256 + t;
            int r = idx >> 6, c = idx & 63;
            tile[r][c] = inh[(size_t)(r0 + r) * HD + c];
        }
        __syncthreads();
#pragma unroll
        for (int i = 0; i < 16; i++) {
            int idx = i * 256 + t;
            int cc = idx >> 6, rr = idx & 63;
            outh[(size_t)cc * SEQ + r0 + rr] = (fp16)tile[rr][cc];
        }
    } else if (bx < 3584) {
        const int zi = bx - 2560;
        const int r0 = (zi >> 5) * 64, c0 = (zi & 31) * 64;
#pragma unroll
        for (int i = 0; i < 16; i++) {
            int idx = i * 256 + t;
            int r = idx >> 6, c = idx & 63;
            tile[r][c] = wo[(size_t)(r0 + r) * 2048 + c0 + c];
        }
        __syncthreads();
#pragma unroll
        for (int i = 0; i < 16; i++) {
            int idx = i * 256 + t;
            int cc = idx >> 6, rr = idx & 63;
            w2t[(size_t)(c0 + cc) * 2048 + r0 + rr] = (fp16)tile[rr][cc];
        }
    } else {
        int idx = (bx - 3584) * 256 + t;  // 0..65535
        int s = idx >> 5, j = idx & 31;
        float invf = expf(-0.28782313662425572f * (float)j);  // 10000^(-j/32)
        float sn, cs;
        sincosf((float)s * invf, &sn, &cs);
        trig[idx] = make_float2(cs, sn);
    }
}

// ============ fused QKV GEMM + RoPE/V-transpose epilogue (table-driven trig) ============
__global__ __launch_bounds__(256) void gemm_qkv_fused(
    const fp16* __restrict__ A, const fp16* __restrict__ Bt, const float2* __restrict__ trig,
    fp16* __restrict__ qb, fp16* __restrict__ kb, fp16* __restrict__ vtb) {
    __shared__ fp16 As[2][64][64];
    __shared__ fp16 Bs[2][128][64];
    const int t = threadIdx.x;
    const int m0 = blockIdx.x * 64, n0 = blockIdx.y * 128;
    const int wid = t >> 6, lane = t & 63;
    const int wm = (wid >> 1) * 32, wn = (wid & 1) * 64;
    const int lr = lane & 15, lg = lane >> 4;
    f32x4 acc[2][4] = {};
    auto stage_ = [&](int kt, int b) {
#pragma unroll
        for (int s = t; s < 512; s += 256) {
            int row = s >> 3, ch = s & 7;
            int lch = ch ^ (row & 7);
            gll16(A + (size_t)(m0 + row) * 2048 + (kt << 6) + lch * 8,
                  (char*)&As[b][0][0] + s * 16);
        }
#pragma unroll
        for (int s = t; s < 1024; s += 256) {
            int row = s >> 3, ch = s & 7;
            int lch = ch ^ (row & 7);
            gll16(Bt + (size_t)(n0 + row) * 2048 + (kt << 6) + lch * 8,
                  (char*)&Bs[b][0][0] + s * 16);
        }
    };
    stage_(0, 0);
    __syncthreads();
    for (int kt = 0; kt < 32; ++kt) {
        const int cur = kt & 1;
        if (kt + 1 < 32) stage_(kt + 1, cur ^ 1);
#pragma unroll
        for (int kk = 0; kk < 2; kk++) {
            half8 af[2], bfv[4];
#pragma unroll
            for (int m = 0; m < 2; m++) {
                int row = wm + m * 16 + lr;
                af[m] = *(const half8*)((const char*)&As[cur][row][0] +
                                        (((kk * 4 + lg) ^ (row & 7)) * 16));
            }
#pragma unroll
            for (int n = 0; n < 4; n++) {
                int row = wn + n * 16 + lr;
                bfv[n] = *(const half8*)((const char*)&Bs[cur][row][0] +
                                         (((kk * 4 + lg) ^ (row & 7)) * 16));
            }
            __builtin_amdgcn_s_setprio(1);
#pragma unroll
            for (int m = 0; m < 2; m++)
#pragma unroll
                for (int n = 0; n < 4; n++)
                    acc[m][n] = __builtin_amdgcn_mfma_f32_16x16x32_f16(af[m], bfv[n], acc[m][n], 0, 0, 0);
            __builtin_amdgcn_s_setprio(0);
        }
        __syncthreads();
    }
    const int head0 = blockIdx.y * 2;
    if (head0 < 40) {
        const int head = head0 + (wid & 1);
        const float qscale = (head0 < 32) ? 0.18033688011112042f : 1.0f;  // 0.125*log2e for q
        fp16* outp = (head0 < 32) ? qb + (size_t)head * SEQ * HD
                                  : kb + (size_t)(head - 32) * SEQ * HD;
#pragma unroll
        for (int n = 0; n < 4; n++) {
            int c = n * 16 + lr;
            int j = c >> 1;
#pragma unroll
            for (int m = 0; m < 2; m++)
#pragma unroll
                for (int r = 0; r < 4; r++) {
                    int s = m0 + wm + m * 16 + lg * 4 + r;
                    float2 tc = trig[s * 32 + j];
                    float val = acc[m][n][r];
                    float pv = __shfl_xor(val, 1);
                    float o = (c & 1) ? (tc.y * pv + tc.x * val) : (tc.x * val - tc.y * pv);
                    outp[(size_t)s * HD + c] = (fp16)(o * qscale);
                }
        }
    } else {
        fp16* T = (fp16*)&Bs[0][0][0];  // [128 cols][stride 68]
#pragma unroll
        for (int n = 0; n < 4; n++)
#pragma unroll
            for (int m = 0; m < 2; m++)
#pragma unroll
                for (int r = 0; r < 4; r++) {
                    int c = wn + n * 16 + lr;
                    int s = wm + m * 16 + lg * 4 + r;
                    T[c * 68 + s] = (fp16)acc[m][n][r];
                }
        __syncthreads();
        const int g0 = head0 - 40;
#pragma unroll
        for (int i = 0; i < 16; i++) {
            int idx = i * 256 + t;
            int c = idx >> 5, sp = (idx & 31) * 2;
            unsigned v = *(const unsigned*)&T[c * 68 + sp];
            *(unsigned*)(vtb + ((size_t)(g0 + (c >> 6)) * 64 + (c & 63)) * SEQ + m0 + sp) = v;
        }
    }
}

// ============ Templated GEMM core (out projection) ============
template <int BM, int BN, int WF32>
__global__ __launch_bounds__(256) void gemm_tpl(
    const fp16* __restrict__ A, const fp16* __restrict__ Bt, void* __restrict__ Cout, int Nout) {
    __shared__ fp16 As[2][BM][64];
    __shared__ fp16 Bs[2][BN][64];
    const int t = threadIdx.x;
    const int m0 = blockIdx.x * BM, n0 = blockIdx.y * BN;
    const int wid = t >> 6, lane = t & 63;
    const int wm = (wid >> 1) * (BM / 2), wn = (wid & 1) * (BN / 2);
    const int lr = lane & 15, lg = lane >> 4;
    constexpr int MR = BM / 32, NR = BN / 32;
    f32x4 acc[MR][NR] = {};
    auto stage_ = [&](int kt, int b) {
#pragma unroll
        for (int s = t; s < BM * 8; s += 256) {
            int row = s >> 3, ch = s & 7;
            int lch = ch ^ (row & 7);
            gll16(A + (size_t)(m0 + row) * 2048 + (kt << 6) + lch * 8,
                  (char*)&As[b][0][0] + s * 16);
        }
#pragma unroll
        for (int s = t; s < BN * 8; s += 256) {
            int row = s >> 3, ch = s & 7;
            int lch = ch ^ (row & 7);
            gll16(Bt + (size_t)(n0 + row) * 2048 + (kt << 6) + lch * 8,
                  (char*)&Bs[b][0][0] + s * 16);
        }
    };
    stage_(0, 0);
    __syncthreads();
    for (int kt = 0; kt < 32; ++kt) {
        const int cur = kt & 1;
        if (kt + 1 < 32) stage_(kt + 1, cur ^ 1);
#pragma unroll
        for (int kk = 0; kk < 2; kk++) {
            half8 af[MR], bfv[NR];
#pragma unroll
            for (int m = 0; m < MR; m++) {
                int row = wm + m * 16 + lr;
                af[m] = *(const half8*)((const char*)&As[cur][row][0] +
                                        (((kk * 4 + lg) ^ (row & 7)) * 16));
            }
#pragma unroll
            for (int n = 0; n < NR; n++) {
                int row = wn + n * 16 + lr;
                bfv[n] = *(const half8*)((const char*)&Bs[cur][row][0] +
                                         (((kk * 4 + lg) ^ (row & 7)) * 16));
            }
            __builtin_amdgcn_s_setprio(1);
#pragma unroll
            for (int m = 0; m < MR; m++)
#pragma unroll
                for (int n = 0; n < NR; n++)
                    acc[m][n] = __builtin_amdgcn_mfma_f32_16x16x32_f16(af[m], bfv[n], acc[m][n], 0, 0, 0);
            __builtin_amdgcn_s_setprio(0);
        }
        __syncthreads();
    }
#pragma unroll
    for (int m = 0; m < MR; m++)
#pragma unroll
        for (int n = 0; n < NR; n++)
#pragma unroll
            for (int r = 0; r < 4; r++) {
                int row = m0 + wm + m * 16 + lg * 4 + r;
                int col = n0 + wn + n * 16 + lr;
                if (WF32)
                    ((float*)Cout)[(size_t)row * Nout + col] = acc[m][n][r];
                else
                    ((fp16*)Cout)[(size_t)row * Nout + col] = (fp16)acc[m][n][r];
            }
}

// ---------------- causal flash attention (r16 body + hoisted addressing + max3 tree) ----
// sc = mfma(K_frag, Q_frag): lane (lr,lg) reg r holds S[kv=kv0+f*16+lg*4+r][q=qr0+lr], log2 units.
// All staging/LDS addresses strength-reduced: byte pointers advance by constant strides per tile.
__global__ __launch_bounds__(256) void attn_kernel(
    const fp16* __restrict__ qb, const fp16* __restrict__ kb,
    const fp16* __restrict__ vt, fp16* __restrict__ o_all) {
    __shared__ fp16 Kb[2][64][64];  // 16 KB (16B-chunk XOR swizzled); buf stride 8192 B
    __shared__ fp16 Vb[2][64][64];  // 16 KB (swizzled); buf stride 8192 B
    __shared__ fp16 P[4][16][64];   //  8 KB per-wave [q=lr][kv] -> 40960 B total
    const int t = threadIdx.x, wid = t >> 6, lane = t & 63;
    const int bx = blockIdx.x;
    const int grp = bx >> 5;
    const int a = grp & 7;
    const int sel = grp >> 3;
    const int qt = (sel == 0) ? (31 - a) : (sel == 1) ? (8 + a) : (sel == 2) ? (23 - a) : a;
    const int head = bx & 31;
    const int g = head >> 2;
    const int lr = lane & 15, lg = lane >> 4;
    const fp16* qh = qb + (size_t)head * SEQ * HD;
    const fp16* kh = kb + (size_t)g * SEQ * HD;
    const fp16* vh = vt + (size_t)g * HD * SEQ;
    const int srow = lane >> 3, schunk = lane & 7;
    const int qr0 = qt * 64 + wid * 16;
    char* pb = (char*)&P[wid][0][0];

    half8 aq0 = *reinterpret_cast<const half8*>(qh + (size_t)(qr0 + lr) * HD + lg * 8);
    half8 aq1 = *reinterpret_cast<const half8*>(qh + (size_t)(qr0 + lr) * HD + 32 + lg * 8);
    f32x4 o[4] = {};
    float m_ = -1e30f, lsum_ = 0.0f;  // per-lane: q = qr0 + lr
    const int nt = qt + 1;

    // ---- hoisted staging state: byte pointers, constant strides per tile ----
    const char* kga = (const char*)kh + (size_t)((wid * 16 + srow) * 64 + (schunk ^ srow) * 8) * 2;
    const char* vga = (const char*)vh + ((size_t)(wid * 16 + srow) * 2048 + (size_t)((schunk ^ srow) * 8)) * 2;
    char* kd0 = (char*)&Kb[0][wid * 16][0];
    char* vd0 = (char*)&Vb[0][wid * 16][0];
    int sb = 0;
    auto stage = [&]() {
        char* kdst = kd0 + sb * 8192;
        char* vdst = vd0 + sb * 8192;
        gll16(kga, kdst);
        gll16(kga + 1024, kdst + 1024);    // +8 K-rows (8*128B), LDS +8 rows
        gll16(vga, vdst);
        gll16(vga + 32768, vdst + 1024);   // +8 V-rows (8*4096B)
        kga += 8192;  // next kv tile: +64 rows * 128 B
        vga += 128;   // next kv tile: +64 cols * 2 B
        sb ^= 1;
    };

    // ---- hoisted LDS offsets (loop-invariant per lane) ----
    int koff[4][2];
#pragma unroll
    for (int f = 0; f < 4; f++) {
        int row = f * 16 + lr;
        koff[f][0] = row * 128 + ((lg ^ (row & 7)) * 16);
        koff[f][1] = row * 128 + (((4 + lg) ^ (row & 7)) * 16);
    }
    int voff[2][4];
#pragma unroll
    for (int h = 0; h < 2; h++)
#pragma unroll
        for (int vf = 0; vf < 4; vf++) {
            int d = vf * 16 + lr;
            voff[h][vf] = d * 128 + (((h * 4 + lg) ^ (d & 7)) * 16);
        }
    int pwoff[4];
#pragma unroll
    for (int f = 0; f < 4; f++) pwoff[f] = lr * 128 + ((f * 32 + lg * 8) ^ ((lr & 7) << 4));
    int proff[2];
#pragma unroll
    for (int h = 0; h < 2; h++) proff[h] = lr * 128 + (((h * 4 + lg) ^ (lr & 7)) * 16);

    stage();  // tile 0 -> buf 0
    __syncthreads();
    for (int tt = 0; tt < nt; ++tt) {
        const int cur = tt & 1;
        if (tt + 1 < nt) stage();
        const int kv0 = tt << 6;
        const char* kbb = (const char*)&Kb[0][0][0] + cur * 8192;
        const char* vbb = (const char*)&Vb[0][0][0] + cur * 8192;
        f32x4 sc[4];
        __builtin_amdgcn_s_setprio(1);
#pragma unroll
        for (int f = 0; f < 4; ++f) {
            half8 b0 = *(const half8*)(kbb + koff[f][0]);
            half8 b1 = *(const half8*)(kbb + koff[f][1]);
            f32x4 s = {};
            s = __builtin_amdgcn_mfma_f32_16x16x32_f16(b0, aq0, s, 0, 0, 0);  // swapped
            s = __builtin_amdgcn_mfma_f32_16x16x32_f16(b1, aq1, s, 0, 0, 0);
            sc[f] = s;
        }
        __builtin_amdgcn_s_setprio(0);
        if (tt == qt) {
            const int q = qr0 + lr;
#pragma unroll
            for (int f = 0; f < 4; f++)
#pragma unroll
                for (int r = 0; r < 4; r++) {
                    int kv = kv0 + f * 16 + lg * 4 + r;
                    if (kv > q) sc[f][r] = -1e30f;
                }
        }
        // ---- defer-max (log2 domain, threshold 11), max3-shaped tree ----
        float t0 = fmaxf(fmaxf(sc[0][0], sc[0][1]), sc[0][2]);
        float t1 = fmaxf(fmaxf(sc[0][3], sc[1][0]), sc[1][1]);
        float t2 = fmaxf(fmaxf(sc[1][2], sc[1][3]), sc[2][0]);
        float t3 = fmaxf(fmaxf(sc[2][1], sc[2][2]), sc[2][3]);
        float t4 = fmaxf(fmaxf(sc[3][0], sc[3][1]), sc[3][2]);
        float lmax = fmaxf(fmaxf(fmaxf(t0, t1), t2), fmaxf(fmaxf(t3, t4), sc[3][3]));
        if (!__all(lmax <= m_ + 11.0f)) {  // rare: reduce across the 4 kv-group lanes of each q
            float v = lmax;
            v = fmaxf(v, __shfl_xor(v, 16));
            v = fmaxf(v, __shfl_xor(v, 32));
            float mn = fmaxf(m_, v);
            float alpha = exp2f(m_ - mn);
            m_ = mn;
            lsum_ *= alpha;
            float al[4];
#pragma unroll
            for (int r = 0; r < 4; r++) al[r] = __shfl(alpha, lg * 4 + r);
#pragma unroll
            for (int vf = 0; vf < 4; vf++)
#pragma unroll
                for (int r = 0; r < 4; r++) o[vf][r] *= al[r];
        }
        // ---- exp2, lane-partial lsum, pack pairs, 4 swizzled b64 P-writes ----
#pragma unroll
        for (int f = 0; f < 4; f++) {
            float p0 = exp2f(sc[f][0] - m_);
            float p1 = exp2f(sc[f][1] - m_);
            float p2 = exp2f(sc[f][2] - m_);
            float p3 = exp2f(sc[f][3] - m_);
            lsum_ += (p0 + p1) + (p2 + p3);
            fp16raw2 k0 = __builtin_amdgcn_cvt_pkrtz(p0, p1);
            fp16raw2 k1 = __builtin_amdgcn_cvt_pkrtz(p2, p3);
            uint2 w;
            w.x = __builtin_bit_cast(unsigned int, k0);
            w.y = __builtin_bit_cast(unsigned int, k1);
            *(uint2*)(pb + pwoff[f]) = w;
        }
        // ---- PV: pa = A-frag of P (row=q=lr, k=kv=h*32+lg*8+b) ----
        __builtin_amdgcn_s_setprio(1);
#pragma unroll
        for (int h = 0; h < 2; h++) {
            half8 pa = *(const half8*)(pb + proff[h]);
#pragma unroll
            for (int vf = 0; vf < 4; vf++) {
                half8 bv = *(const half8*)(vbb + voff[h][vf]);
                o[vf] = __builtin_amdgcn_mfma_f32_16x16x32_f16(pa, bv, o[vf], 0, 0, 0);
            }
        }
        __builtin_amdgcn_s_setprio(0);
        __syncthreads();  // drains vmcnt (stage of tt+1) + protects buffer reuse
    }
    // final: reduce lsum across kv-group lanes, broadcast to (lg,r) indexing, write
    lsum_ += __shfl_xor(lsum_, 16);
    lsum_ += __shfl_xor(lsum_, 32);
    float li[4];
#pragma unroll
    for (int r = 0; r < 4; r++) li[r] = 1.0f / __shfl(lsum_, lg * 4 + r);
#pragma unroll
    for (int vf = 0; vf < 4; vf++)
#pragma unroll
        for (int r = 0; r < 4; r++) {
            float v = o[vf][r] * li[r];
            o_all[(size_t)(qr0 + lg * 4 + r) * 2048 + head * 64 + vf * 16 + lr] = (fp16)v;
        }
}

extern "C" void kernel_launch(void* const* d_in, const int* in_sizes, int n_in,
                              void* d_out, int out_size, void* d_ws, size_t ws_size,
                              hipStream_t stream) {
    const float* x  = (const float*)d_in[0];
    const float* wq = (const float*)d_in[1];
    const float* wk = (const float*)d_in[2];
    const float* wv = (const float*)d_in[3];
    const float* wo = (const float*)d_in[4];
    float* out = (float*)d_out;
    char* ws = (char*)d_ws;

    // Workspace (48.5 MB peak).
    fp16*   xh    = (fp16*)(ws);                        // 8 MB  [2048][2048]
    fp16*   wqkvt = (fp16*)(ws + ((size_t)8 << 20));    // 12 MB [3072][2048]
    fp16*   o_all = (fp16*)(ws + ((size_t)20 << 20));   // 8 MB  [2048][2048]
    fp16*   w2t   = (fp16*)(ws + ((size_t)28 << 20));   // 8 MB  [2048 d][2048 hv]
    fp16*   qbuf  = (fp16*)(ws + ((size_t)36 << 20));   // 8 MB  [32][2048][64]
    fp16*   kbuf  = (fp16*)(ws + ((size_t)44 << 20));   // 2 MB  [8][2048][64]
    fp16*   vtb   = (fp16*)(ws + ((size_t)46 << 20));   // 2 MB  [8][64][2048]
    float2* trig  = (float2*)(ws + ((size_t)48 << 20)); // 512 KB [2048][32]

    prep_kernel<<<dim3(3840), 256, 0, stream>>>(x, wq, wk, wv, wo, xh, wqkvt, w2t, trig);
    gemm_qkv_fused<<<dim3(32, 24), 256, 0, stream>>>(xh, wqkvt, trig, qbuf, kbuf, vtb);
    attn_kernel<<<dim3(1024), 256, 0, stream>>>(qbuf, kbuf, vtb, o_all);
    gemm_tpl<64, 128, 1><<<dim3(32, 16), 256, 0, stream>>>(o_all, w2t, out, 2048);
}

// Round 21
// 122.013 us; speedup vs baseline: 1.0438x; 1.0438x over previous
//
#include <hip/hip_runtime.h>
#include <hip/hip_bf16.h>

#define SEQ 2048
#define DIMM 2048
#define NQH 32
#define NKVH 8
#define HD 64

typedef _Float16 half8 __attribute__((ext_vector_type(8)));
typedef float f32x4 __attribute__((ext_vector_type(4)));
typedef __fp16 fp16raw2 __attribute__((ext_vector_type(2)));
using fp16 = _Float16;

typedef __attribute__((address_space(1))) unsigned int ga_u32;
typedef __attribute__((address_space(3))) unsigned int ls_u32;

__device__ __forceinline__ void gll16(const void* g, void* l) {
    __builtin_amdgcn_global_load_lds((const ga_u32*)g, (ls_u32*)l, 16, 0, 0);
}

// native 2^x: single v_exp_f32 (inputs are in-range: <= ~11, or -1e30 -> 0)
__device__ __forceinline__ float fexp2(float x) {
#if __has_builtin(__builtin_amdgcn_exp2f)
    return __builtin_amdgcn_exp2f(x);
#else
    float r;
    asm("v_exp_f32 %0, %1" : "=v"(r) : "v"(x));
    return r;
#endif
}

// ============ merged prep: cast x, transpose wq/wk/wv, transpose w_out, RoPE trig table ============
__global__ void prep_kernel(const float* __restrict__ x,
                            const float* __restrict__ wq, const float* __restrict__ wk,
                            const float* __restrict__ wv, const float* __restrict__ wo,
                            fp16* __restrict__ xh, fp16* __restrict__ wqkvt,
                            fp16* __restrict__ w2t, float2* __restrict__ trig) {
    __shared__ float tile[64][65];
    const int bx = blockIdx.x;
    const int t = threadIdx.x;
    if (bx < 1024) {
#pragma unroll
        for (int it = 0; it < 4; it++) {
            int i = bx * 4096 + it * 1024 + t * 4;
            float4 v = *reinterpret_cast<const float4*>(x + i);
            fp16* o = xh + i;
            o[0] = (fp16)v.x; o[1] = (fp16)v.y; o[2] = (fp16)v.z; o[3] = (fp16)v.w;
        }
    } else if (bx < 2560) {
        const int zi = bx - 1024;
        const int z = zi >> 5;
        const int r0 = (zi & 31) * 64;
        const float* inh = (z < 32) ? wq + (size_t)z * SEQ * HD
                                    : (z < 40) ? wk + (size_t)(z - 32) * SEQ * HD
                                               : wv + (size_t)(z - 40) * SEQ * HD;
        fp16* outh = wqkvt + (size_t)z * HD * SEQ;
#pragma unroll
        for (int i = 0; i < 16; i++) {
            int idx = i * 256 + t;
            int r = idx >> 6, c = idx & 63;
            tile[r][c] = inh[(size_t)(r0 + r) * HD + c];
        }
        __syncthreads();
#pragma unroll
        for (int i = 0; i < 16; i++) {
            int idx = i * 256 + t;
            int cc = idx >> 6, rr = idx & 63;
            outh[(size_t)cc * SEQ + r0 + rr] = (fp16)tile[rr][cc];
        }
    } else if (bx < 3584) {
        const int zi = bx - 2560;
        const int r0 = (zi >> 5) * 64, c0 = (zi & 31) * 64;
#pragma unroll
        for (int i = 0; i < 16; i++) {
            int idx = i * 256 + t;
            int r = idx >> 6, c = idx & 63;
            tile[r][c] = wo[(size_t)(r0 + r) * 2048 + c0 + c];
        }
        __syncthreads();
#pragma unroll
        for (int i = 0; i < 16; i++) {
            int idx = i * 256 + t;
            int cc = idx >> 6, rr = idx & 63;
            w2t[(size_t)(c0 + cc) * 2048 + r0 + rr] = (fp16)tile[rr][cc];
        }
    } else {
        int idx = (bx - 3584) * 256 + t;  // 0..65535
        int s = idx >> 5, j = idx & 31;
        float invf = expf(-0.28782313662425572f * (float)j);  // 10000^(-j/32)
        float sn, cs;
        sincosf((float)s * invf, &sn, &cs);
        trig[idx] = make_float2(cs, sn);
    }
}

// ============ fused QKV GEMM + RoPE/V-transpose epilogue (table-driven trig) ============
__global__ __launch_bounds__(256) void gemm_qkv_fused(
    const fp16* __restrict__ A, const fp16* __restrict__ Bt, const float2* __restrict__ trig,
    fp16* __restrict__ qb, fp16* __restrict__ kb, fp16* __restrict__ vtb) {
    __shared__ fp16 As[2][64][64];
    __shared__ fp16 Bs[2][128][64];
    const int t = threadIdx.x;
    const int m0 = blockIdx.x * 64, n0 = blockIdx.y * 128;
    const int wid = t >> 6, lane = t & 63;
    const int wm = (wid >> 1) * 32, wn = (wid & 1) * 64;
    const int lr = lane & 15, lg = lane >> 4;
    f32x4 acc[2][4] = {};
    auto stage_ = [&](int kt, int b) {
#pragma unroll
        for (int s = t; s < 512; s += 256) {
            int row = s >> 3, ch = s & 7;
            int lch = ch ^ (row & 7);
            gll16(A + (size_t)(m0 + row) * 2048 + (kt << 6) + lch * 8,
                  (char*)&As[b][0][0] + s * 16);
        }
#pragma unroll
        for (int s = t; s < 1024; s += 256) {
            int row = s >> 3, ch = s & 7;
            int lch = ch ^ (row & 7);
            gll16(Bt + (size_t)(n0 + row) * 2048 + (kt << 6) + lch * 8,
                  (char*)&Bs[b][0][0] + s * 16);
        }
    };
    stage_(0, 0);
    __syncthreads();
    for (int kt = 0; kt < 32; ++kt) {
        const int cur = kt & 1;
        if (kt + 1 < 32) stage_(kt + 1, cur ^ 1);
#pragma unroll
        for (int kk = 0; kk < 2; kk++) {
            half8 af[2], bfv[4];
#pragma unroll
            for (int m = 0; m < 2; m++) {
                int row = wm + m * 16 + lr;
                af[m] = *(const half8*)((const char*)&As[cur][row][0] +
                                        (((kk * 4 + lg) ^ (row & 7)) * 16));
            }
#pragma unroll
            for (int n = 0; n < 4; n++) {
                int row = wn + n * 16 + lr;
                bfv[n] = *(const half8*)((const char*)&Bs[cur][row][0] +
                                         (((kk * 4 + lg) ^ (row & 7)) * 16));
            }
            __builtin_amdgcn_s_setprio(1);
#pragma unroll
            for (int m = 0; m < 2; m++)
#pragma unroll
                for (int n = 0; n < 4; n++)
                    acc[m][n] = __builtin_amdgcn_mfma_f32_16x16x32_f16(af[m], bfv[n], acc[m][n], 0, 0, 0);
            __builtin_amdgcn_s_setprio(0);
        }
        __syncthreads();
    }
    const int head0 = blockIdx.y * 2;
    if (head0 < 40) {
        const int head = head0 + (wid & 1);
        const float qscale = (head0 < 32) ? 0.18033688011112042f : 1.0f;  // 0.125*log2e for q
        fp16* outp = (head0 < 32) ? qb + (size_t)head * SEQ * HD
                                  : kb + (size_t)(head - 32) * SEQ * HD;
#pragma unroll
        for (int n = 0; n < 4; n++) {
            int c = n * 16 + lr;
            int j = c >> 1;
#pragma unroll
            for (int m = 0; m < 2; m++)
#pragma unroll
                for (int r = 0; r < 4; r++) {
                    int s = m0 + wm + m * 16 + lg * 4 + r;
                    float2 tc = trig[s * 32 + j];
                    float val = acc[m][n][r];
                    float pv = __shfl_xor(val, 1);
                    float o = (c & 1) ? (tc.y * pv + tc.x * val) : (tc.x * val - tc.y * pv);
                    outp[(size_t)s * HD + c] = (fp16)(o * qscale);
                }
        }
    } else {
        fp16* T = (fp16*)&Bs[0][0][0];  // [128 cols][stride 68]
#pragma unroll
        for (int n = 0; n < 4; n++)
#pragma unroll
            for (int m = 0; m < 2; m++)
#pragma unroll
                for (int r = 0; r < 4; r++) {
                    int c = wn + n * 16 + lr;
                    int s = wm + m * 16 + lg * 4 + r;
                    T[c * 68 + s] = (fp16)acc[m][n][r];
                }
        __syncthreads();
        const int g0 = head0 - 40;
#pragma unroll
        for (int i = 0; i < 16; i++) {
            int idx = i * 256 + t;
            int c = idx >> 5, sp = (idx & 31) * 2;
            unsigned v = *(const unsigned*)&T[c * 68 + sp];
            *(unsigned*)(vtb + ((size_t)(g0 + (c >> 6)) * 64 + (c & 63)) * SEQ + m0 + sp) = v;
        }
    }
}

// ============ Templated GEMM core (out projection) ============
template <int BM, int BN, int WF32>
__global__ __launch_bounds__(256) void gemm_tpl(
    const fp16* __restrict__ A, const fp16* __restrict__ Bt, void* __restrict__ Cout, int Nout) {
    __shared__ fp16 As[2][BM][64];
    __shared__ fp16 Bs[2][BN][64];
    const int t = threadIdx.x;
    const int m0 = blockIdx.x * BM, n0 = blockIdx.y * BN;
    const int wid = t >> 6, lane = t & 63;
    const int wm = (wid >> 1) * (BM / 2), wn = (wid & 1) * (BN / 2);
    const int lr = lane & 15, lg = lane >> 4;
    constexpr int MR = BM / 32, NR = BN / 32;
    f32x4 acc[MR][NR] = {};
    auto stage_ = [&](int kt, int b) {
#pragma unroll
        for (int s = t; s < BM * 8; s += 256) {
            int row = s >> 3, ch = s & 7;
            int lch = ch ^ (row & 7);
            gll16(A + (size_t)(m0 + row) * 2048 + (kt << 6) + lch * 8,
                  (char*)&As[b][0][0] + s * 16);
        }
#pragma unroll
        for (int s = t; s < BN * 8; s += 256) {
            int row = s >> 3, ch = s & 7;
            int lch = ch ^ (row & 7);
            gll16(Bt + (size_t)(n0 + row) * 2048 + (kt << 6) + lch * 8,
                  (char*)&Bs[b][0][0] + s * 16);
        }
    };
    stage_(0, 0);
    __syncthreads();
    for (int kt = 0; kt < 32; ++kt) {
        const int cur = kt & 1;
        if (kt + 1 < 32) stage_(kt + 1, cur ^ 1);
#pragma unroll
        for (int kk = 0; kk < 2; kk++) {
            half8 af[MR], bfv[NR];
#pragma unroll
            for (int m = 0; m < MR; m++) {
                int row = wm + m * 16 + lr;
                af[m] = *(const half8*)((const char*)&As[cur][row][0] +
                                        (((kk * 4 + lg) ^ (row & 7)) * 16));
            }
#pragma unroll
            for (int n = 0; n < NR; n++) {
                int row = wn + n * 16 + lr;
                bfv[n] = *(const half8*)((const char*)&Bs[cur][row][0] +
                                         (((kk * 4 + lg) ^ (row & 7)) * 16));
            }
            __builtin_amdgcn_s_setprio(1);
#pragma unroll
            for (int m = 0; m < MR; m++)
#pragma unroll
                for (int n = 0; n < NR; n++)
                    acc[m][n] = __builtin_amdgcn_mfma_f32_16x16x32_f16(af[m], bfv[n], acc[m][n], 0, 0, 0);
            __builtin_amdgcn_s_setprio(0);
        }
        __syncthreads();
    }
#pragma unroll
    for (int m = 0; m < MR; m++)
#pragma unroll
        for (int n = 0; n < NR; n++)
#pragma unroll
            for (int r = 0; r < 4; r++) {
                int row = m0 + wm + m * 16 + lg * 4 + r;
                int col = n0 + wn + n * 16 + lr;
                if (WF32)
                    ((float*)Cout)[(size_t)row * Nout + col] = acc[m][n][r];
                else
                    ((fp16*)Cout)[(size_t)row * Nout + col] = (fp16)acc[m][n][r];
            }
}

// ---------------- causal flash attention (r20 body, native v_exp_f32 softmax) ----
__global__ __launch_bounds__(256) void attn_kernel(
    const fp16* __restrict__ qb, const fp16* __restrict__ kb,
    const fp16* __restrict__ vt, fp16* __restrict__ o_all) {
    __shared__ fp16 Kb[2][64][64];  // 16 KB (16B-chunk XOR swizzled); buf stride 8192 B
    __shared__ fp16 Vb[2][64][64];  // 16 KB (swizzled); buf stride 8192 B
    __shared__ fp16 P[4][16][64];   //  8 KB per-wave [q=lr][kv] -> 40960 B total
    const int t = threadIdx.x, wid = t >> 6, lane = t & 63;
    const int bx = blockIdx.x;
    const int grp = bx >> 5;
    const int a = grp & 7;
    const int sel = grp >> 3;
    const int qt = (sel == 0) ? (31 - a) : (sel == 1) ? (8 + a) : (sel == 2) ? (23 - a) : a;
    const int head = bx & 31;
    const int g = head >> 2;
    const int lr = lane & 15, lg = lane >> 4;
    const fp16* qh = qb + (size_t)head * SEQ * HD;
    const fp16* kh = kb + (size_t)g * SEQ * HD;
    const fp16* vh = vt + (size_t)g * HD * SEQ;
    const int srow = lane >> 3, schunk = lane & 7;
    const int qr0 = qt * 64 + wid * 16;
    char* pb = (char*)&P[wid][0][0];

    half8 aq0 = *reinterpret_cast<const half8*>(qh + (size_t)(qr0 + lr) * HD + lg * 8);
    half8 aq1 = *reinterpret_cast<const half8*>(qh + (size_t)(qr0 + lr) * HD + 32 + lg * 8);
    f32x4 o[4] = {};
    float m_ = -1e30f, lsum_ = 0.0f;  // per-lane: q = qr0 + lr
    const int nt = qt + 1;

    const char* kga = (const char*)kh + (size_t)((wid * 16 + srow) * 64 + (schunk ^ srow) * 8) * 2;
    const char* vga = (const char*)vh + ((size_t)(wid * 16 + srow) * 2048 + (size_t)((schunk ^ srow) * 8)) * 2;
    char* kd0 = (char*)&Kb[0][wid * 16][0];
    char* vd0 = (char*)&Vb[0][wid * 16][0];
    int sb = 0;
    auto stage = [&]() {
        char* kdst = kd0 + sb * 8192;
        char* vdst = vd0 + sb * 8192;
        gll16(kga, kdst);
        gll16(kga + 1024, kdst + 1024);    // +8 K-rows
        gll16(vga, vdst);
        gll16(vga + 32768, vdst + 1024);   // +8 V-rows
        kga += 8192;
        vga += 128;
        sb ^= 1;
    };

    int koff[4][2];
#pragma unroll
    for (int f = 0; f < 4; f++) {
        int row = f * 16 + lr;
        koff[f][0] = row * 128 + ((lg ^ (row & 7)) * 16);
        koff[f][1] = row * 128 + (((4 + lg) ^ (row & 7)) * 16);
    }
    int voff[2][4];
#pragma unroll
    for (int h = 0; h < 2; h++)
#pragma unroll
        for (int vf = 0; vf < 4; vf++) {
            int d = vf * 16 + lr;
            voff[h][vf] = d * 128 + (((h * 4 + lg) ^ (d & 7)) * 16);
        }
    int pwoff[4];
#pragma unroll
    for (int f = 0; f < 4; f++) pwoff[f] = lr * 128 + ((f * 32 + lg * 8) ^ ((lr & 7) << 4));
    int proff[2];
#pragma unroll
    for (int h = 0; h < 2; h++) proff[h] = lr * 128 + (((h * 4 + lg) ^ (lr & 7)) * 16);

    stage();  // tile 0 -> buf 0
    __syncthreads();
    for (int tt = 0; tt < nt; ++tt) {
        const int cur = tt & 1;
        if (tt + 1 < nt) stage();
        const int kv0 = tt << 6;
        const char* kbb = (const char*)&Kb[0][0][0] + cur * 8192;
        const char* vbb = (const char*)&Vb[0][0][0] + cur * 8192;
        f32x4 sc[4];
        __builtin_amdgcn_s_setprio(1);
#pragma unroll
        for (int f = 0; f < 4; ++f) {
            half8 b0 = *(const half8*)(kbb + koff[f][0]);
            half8 b1 = *(const half8*)(kbb + koff[f][1]);
            f32x4 s = {};
            s = __builtin_amdgcn_mfma_f32_16x16x32_f16(b0, aq0, s, 0, 0, 0);  // swapped
            s = __builtin_amdgcn_mfma_f32_16x16x32_f16(b1, aq1, s, 0, 0, 0);
            sc[f] = s;
        }
        __builtin_amdgcn_s_setprio(0);
        if (tt == qt) {
            const int q = qr0 + lr;
#pragma unroll
            for (int f = 0; f < 4; f++)
#pragma unroll
                for (int r = 0; r < 4; r++) {
                    int kv = kv0 + f * 16 + lg * 4 + r;
                    if (kv > q) sc[f][r] = -1e30f;
                }
        }
        // ---- defer-max (log2 domain, threshold 11), max3-shaped tree ----
        float t0 = fmaxf(fmaxf(sc[0][0], sc[0][1]), sc[0][2]);
        float t1 = fmaxf(fmaxf(sc[0][3], sc[1][0]), sc[1][1]);
        float t2 = fmaxf(fmaxf(sc[1][2], sc[1][3]), sc[2][0]);
        float t3 = fmaxf(fmaxf(sc[2][1], sc[2][2]), sc[2][3]);
        float t4 = fmaxf(fmaxf(sc[3][0], sc[3][1]), sc[3][2]);
        float lmax = fmaxf(fmaxf(fmaxf(t0, t1), t2), fmaxf(fmaxf(t3, t4), sc[3][3]));
        if (!__all(lmax <= m_ + 11.0f)) {  // rare path
            float v = lmax;
            v = fmaxf(v, __shfl_xor(v, 16));
            v = fmaxf(v, __shfl_xor(v, 32));
            float mn = fmaxf(m_, v);
            float alpha = fexp2(m_ - mn);
            m_ = mn;
            lsum_ *= alpha;
            float al[4];
#pragma unroll
            for (int r = 0; r < 4; r++) al[r] = __shfl(alpha, lg * 4 + r);
#pragma unroll
            for (int vf = 0; vf < 4; vf++)
#pragma unroll
                for (int r = 0; r < 4; r++) o[vf][r] *= al[r];
        }
        // ---- native exp2, lane-partial lsum, pack pairs, 4 swizzled b64 P-writes ----
#pragma unroll
        for (int f = 0; f < 4; f++) {
            float p0 = fexp2(sc[f][0] - m_);
            float p1 = fexp2(sc[f][1] - m_);
            float p2 = fexp2(sc[f][2] - m_);
            float p3 = fexp2(sc[f][3] - m_);
            lsum_ += (p0 + p1) + (p2 + p3);
            fp16raw2 k0 = __builtin_amdgcn_cvt_pkrtz(p0, p1);
            fp16raw2 k1 = __builtin_amdgcn_cvt_pkrtz(p2, p3);
            uint2 w;
            w.x = __builtin_bit_cast(unsigned int, k0);
            w.y = __builtin_bit_cast(unsigned int, k1);
            *(uint2*)(pb + pwoff[f]) = w;
        }
        // ---- PV: pa = A-frag of P (row=q=lr, k=kv=h*32+lg*8+b) ----
        __builtin_amdgcn_s_setprio(1);
#pragma unroll
        for (int h = 0; h < 2; h++) {
            half8 pa = *(const half8*)(pb + proff[h]);
#pragma unroll
            for (int vf = 0; vf < 4; vf++) {
                half8 bv = *(const half8*)(vbb + voff[h][vf]);
                o[vf] = __builtin_amdgcn_mfma_f32_16x16x32_f16(pa, bv, o[vf], 0, 0, 0);
            }
        }
        __builtin_amdgcn_s_setprio(0);
        __syncthreads();  // drains vmcnt (stage of tt+1) + protects buffer reuse
    }
    // final: reduce lsum across kv-group lanes, broadcast to (lg,r) indexing, write
    lsum_ += __shfl_xor(lsum_, 16);
    lsum_ += __shfl_xor(lsum_, 32);
    float li[4];
#pragma unroll
    for (int r = 0; r < 4; r++) li[r] = 1.0f / __shfl(lsum_, lg * 4 + r);
#pragma unroll
    for (int vf = 0; vf < 4; vf++)
#pragma unroll
        for (int r = 0; r < 4; r++) {
            float v = o[vf][r] * li[r];
            o_all[(size_t)(qr0 + lg * 4 + r) * 2048 + head * 64 + vf * 16 + lr] = (fp16)v;
        }
}

extern "C" void kernel_launch(void* const* d_in, const int* in_sizes, int n_in,
                              void* d_out, int out_size, void* d_ws, size_t ws_size,
                              hipStream_t stream) {
    const float* x  = (const float*)d_in[0];
    const float* wq = (const float*)d_in[1];
    const float* wk = (const float*)d_in[2];
    const float* wv = (const float*)d_in[3];
    const float* wo = (const float*)d_in[4];
    float* out = (float*)d_out;
    char* ws = (char*)d_ws;

    // Workspace (48.5 MB peak).
    fp16*   xh    = (fp16*)(ws);                        // 8 MB  [2048][2048]
    fp16*   wqkvt = (fp16*)(ws + ((size_t)8 << 20));    // 12 MB [3072][2048]
    fp16*   o_all = (fp16*)(ws + ((size_t)20 << 20));   // 8 MB  [2048][2048]
    fp16*   w2t   = (fp16*)(ws + ((size_t)28 << 20));   // 8 MB  [2048 d][2048 hv]
    fp16*   qbuf  = (fp16*)(ws + ((size_t)36 << 20));   // 8 MB  [32][2048][64]
    fp16*   kbuf  = (fp16*)(ws + ((size_t)44 << 20));   // 2 MB  [8][2048][64]
    fp16*   vtb   = (fp16*)(ws + ((size_t)46 << 20));   // 2 MB  [8][64][2048]
    float2* trig  = (float2*)(ws + ((size_t)48 << 20)); // 512 KB [2048][32]

    prep_kernel<<<dim3(3840), 256, 0, stream>>>(x, wq, wk, wv, wo, xh, wqkvt, w2t, trig);
    gemm_qkv_fused<<<dim3(32, 24), 256, 0, stream>>>(xh, wqkvt, trig, qbuf, kbuf, vtb);
    attn_kernel<<<dim3(1024), 256, 0, stream>>>(qbuf, kbuf, vtb, o_all);
    gemm_tpl<64, 128, 1><<<dim3(32, 16), 256, 0, stream>>>(o_all, w2t, out, 2048);
}